// Round 6
// baseline (268.277 us; speedup 1.0000x reference)
//
#include <hip/hip_runtime.h>
#include <math.h>

typedef __attribute__((ext_vector_type(8))) short bf16x8;   // 8 bf16 = 4 VGPRs (MFMA A/B frag)
typedef __attribute__((ext_vector_type(4))) float f32x4;    // MFMA C/D frag
typedef unsigned short u16;
typedef unsigned int u32;

// Problem: B=8, N=1024, C=768, H=8, hd=96.  BH=64 combined batch-heads.

__device__ __forceinline__ u16 f2b(float f) {               // fp32 -> bf16 RNE
  u32 u = __float_as_uint(f);
  return (u16)((u + 0x7fffu + ((u >> 16) & 1u)) >> 16);
}
__device__ __forceinline__ float b2f(u16 h) {
  return __uint_as_float(((u32)h) << 16);
}
__device__ __forceinline__ int swz(int m) { return (m ^ (m >> 2)) & 3; }

__device__ __forceinline__ void async16(const void* g, void* l) {
  __builtin_amdgcn_global_load_lds((const __attribute__((address_space(1))) u32*)g,
                                   (__attribute__((address_space(3))) u32*)l, 16, 0, 0);
}

// ---------------- prep: cast x, transpose+cast w_qkv and w_proj -------------
__global__ __launch_bounds__(256) void prep_kernel(const float* __restrict__ x,
                                                   const float* __restrict__ w_qkv,
                                                   const float* __restrict__ w_proj,
                                                   u16* __restrict__ xb,
                                                   u16* __restrict__ wqkvT,
                                                   u16* __restrict__ wprojT) {
  __shared__ float t[32][33];
  const int blk = blockIdx.x;
  if (blk < 6144) {                       // cast x -> bf16
    const int idx = blk * 256 + threadIdx.x;
    const float4 v = ((const float4*)x)[idx];
    uint2 o;
    o.x = (u32)f2b(v.x) | ((u32)f2b(v.y) << 16);
    o.y = (u32)f2b(v.z) | ((u32)f2b(v.w) << 16);
    ((uint2*)xb)[idx] = o;
    return;
  }
  const float* in; u16* out; int R, C, bx, by;
  if (blk < 6144 + 1728) {                // w_qkv [768,2304] -> [2304,768]
    const int rem = blk - 6144;
    in = w_qkv; out = wqkvT; R = 768; C = 2304; bx = rem % 72; by = rem / 72;
  } else {                                // w_proj [768,768] -> [768,768]
    const int rem = blk - 6144 - 1728;
    in = w_proj; out = wprojT; R = 768; C = 768; bx = rem % 24; by = rem / 24;
  }
  const int c0 = bx * 32, r0 = by * 32;
  const int tc = threadIdx.x & 31, tr = threadIdx.x >> 5;
#pragma unroll
  for (int j = 0; j < 4; ++j)
    t[tr + j * 8][tc] = in[(size_t)(r0 + tr + j * 8) * C + c0 + tc];
  __syncthreads();
#pragma unroll
  for (int j = 0; j < 4; ++j)
    out[(size_t)(c0 + tr + j * 8) * R + r0 + tc] = f2b(t[tc][tr + j * 8]);
}

// ---------------- 128xNT bf16 MFMA GEMM core (K=768), NT in {64,192} --------
template<int NT>
__device__ __forceinline__ void gemm_core(const u16* __restrict__ A,
                                          const u16* __restrict__ Bt,
                                          int m0, int n0, f32x4 acc[4][NT / 32]) {
  constexpr int JT = NT / 32;
  constexpr int NINST = (512 + NT * 4) / 256;
  __shared__ u16 Sm[(512 + NT * 4) * 8];
  const int tid = threadIdx.x;
  const int w = tid >> 6, lane = tid & 63;
  const int i15 = lane & 15, quad = lane >> 4;
  const int wm = (w >> 1) * 64, wn = (w & 1) * (NT / 2);
  const int sw = quad ^ swz(i15);

#pragma unroll
  for (int i = 0; i < 4; ++i)
#pragma unroll
    for (int j = 0; j < JT; ++j) acc[i][j] = (f32x4){0.f, 0.f, 0.f, 0.f};

  for (int k0 = 0; k0 < 768; k0 += 32) {
    __syncthreads();
#pragma unroll
    for (int inst = 0; inst < NINST; ++inst) {
      const int s = inst * 256 + tid;          // granule slot (per lane)
      const u16* src;
      if (inst < 2) {                          // A region (slots < 512)
        const int m = s >> 2, e = s & 3;
        src = A + ((size_t)(m0 + m) * 768 + k0 + (e ^ swz(m)) * 8);
      } else {                                 // B region
        const int s2 = s - 512;
        const int n = s2 >> 2, e = s2 & 3;
        src = Bt + ((size_t)(n0 + n) * 768 + k0 + (e ^ swz(n)) * 8);
      }
      async16(src, (void*)(Sm + (size_t)(inst * 256 + w * 64) * 8));
    }
    __syncthreads();                           // drains vmcnt before reads
    bf16x8 af[4], bf[JT];
#pragma unroll
    for (int i = 0; i < 4; ++i)
      af[i] = *(const bf16x8*)(Sm + ((size_t)(wm + i * 16 + i15) * 4 + sw) * 8);
#pragma unroll
    for (int j = 0; j < JT; ++j)
      bf[j] = *(const bf16x8*)(Sm + ((size_t)512 + (wn + j * 16 + i15) * 4 + sw) * 8);
#pragma unroll
    for (int i = 0; i < 4; ++i)
#pragma unroll
      for (int j = 0; j < JT; ++j)
        acc[i][j] = __builtin_amdgcn_mfma_f32_16x16x32_bf16(af[i], bf[j], acc[i][j], 0, 0, 0);
  }
}

// ---------------- qkv GEMM + fused L2norm/temp epilogue ---------------------
__global__ __launch_bounds__(256, 3) void qkv_gemm_kernel(
    const u16* __restrict__ xb, const u16* __restrict__ wT,
    const float* __restrict__ temp,
    u16* __restrict__ q, u16* __restrict__ k, u16* __restrict__ vT) {
  f32x4 acc[4][6];
  const int bid = blockIdx.x;                 // 768 blocks = 3/CU exact
  const int xcd = bid & 7, slot = bid >> 3;   // 96 slots per XCD
  const int mb = xcd * 8 + slot / 12, nb = slot % 12;
  const int m0 = mb * 128, n0 = nb * 192;
  gemm_core<192>(xb, wT, m0, n0, acc);

  const int tid = threadIdx.x, w = tid >> 6, lane = tid & 63;
  const int i15 = lane & 15, quad = lane >> 4;
  const int wm = (w >> 1) * 64;
  const int three = nb >> 2;                  // 0=q, 1=k, 2=v
  const int h = ((nb & 3) << 1) + (w & 1);    // wave-uniform head

  if (three < 2) {
    u16* dst = three ? k : q;
    const float sc_extra = three ? 1.f : temp[h];
#pragma unroll
    for (int it = 0; it < 4; ++it) {
#pragma unroll
      for (int r = 0; r < 4; ++r) {
        float s = 0.f;
#pragma unroll
        for (int jt = 0; jt < 6; ++jt) s += acc[it][jt][r] * acc[it][jt][r];
        s += __shfl_xor(s, 1); s += __shfl_xor(s, 2);
        s += __shfl_xor(s, 4); s += __shfl_xor(s, 8);
        const float scale = sc_extra / fmaxf(sqrtf(s), 1e-12f);
        const int m = m0 + wm + it * 16 + quad * 4 + r;
        const int b = m >> 10, n = m & 1023;
        u16* rowp = dst + ((size_t)(b * 8 + h) * 1024 + n) * 96;
#pragma unroll
        for (int jt = 0; jt < 6; ++jt)
          rowp[jt * 16 + i15] = f2b(acc[it][jt][r] * scale);
      }
    }
  } else {
#pragma unroll
    for (int it = 0; it < 4; ++it) {
      const int mb4 = m0 + wm + it * 16 + quad * 4;
      const int b = mb4 >> 10, nbase = mb4 & 1023;
#pragma unroll
      for (int jt = 0; jt < 6; ++jt) {
        const int d = jt * 16 + i15;
        uint2 pk;
        pk.x = (u32)f2b(acc[it][jt][0]) | ((u32)f2b(acc[it][jt][1]) << 16);
        pk.y = (u32)f2b(acc[it][jt][2]) | ((u32)f2b(acc[it][jt][3]) << 16);
        *(uint2*)(vT + ((size_t)(b * 8 + h) * 96 + d) * 1024 + nbase) = pk;
      }
    }
  }
}

// ---------------- fused attention: 64 q-rows/block, no split-K --------------
// Grid = 64 bh x 16 q-blocks = 1024 = exactly 4 blocks/CU (R4's 512 capped at
// 2/CU). q-split adds ZERO HBM traffic (unlike R5's split-K): each block reads
// full K/V; same-bh blocks share an XCD so L2 absorbs re-reads (R4: 192 MB
// issued -> 24 MB fetched). Wave owns 16 q-rows; LDS 32 KB (KV 24 + P 8).
__global__ __launch_bounds__(256, 4) void attn_kernel(
    const u16* __restrict__ q, const u16* __restrict__ kk,
    const u16* __restrict__ vT, u16* __restrict__ ctx) {
  __shared__ u16 smem[16384];         // [0,12288): K+V granules; [12288,16384): P
  u16* KVs = smem;
  const int tid = threadIdx.x, w = tid >> 6, lane = tid & 63;
  const int i15 = lane & 15, quad = lane >> 4;
  const int xs = swz(i15);
  const int bh = blockIdx.x & 63;     // same bh -> same XCD (L2-resident K/V)
  const int qbase = (blockIdx.x >> 6) * 64;
  const int b = bh >> 3, h = bh & 7;
  u16* Pw = smem + 12288 + w * 1024;  // per-wave P: 16 rows x 64 keys = 128 granules

  // Q fragments in registers: B-frag n=i15 -> qrow, k=quad*8+j -> d
  bf16x8 qf[3];
  {
    const int qrow = qbase + w * 16 + i15;
    const u16* qp = q + ((size_t)bh * 1024 + qrow) * 96 + quad * 8;
#pragma unroll
    for (int c = 0; c < 3; ++c) qf[c] = *(const bf16x8*)(qp + c * 32);
  }

  f32x4 o[6];
#pragma unroll
  for (int dt = 0; dt < 6; ++dt) o[dt] = (f32x4){0.f, 0.f, 0.f, 0.f};
  float l = 0.f;

  const int key_s = tid >> 2, qs = tid & 3;
  const int kgq = qs ^ swz(key_s);
  int vd[3], vc2[3], vgq[3];
  vd[0] = tid >> 2;                      vc2[0] = 0;
  vd[1] = (tid < 128) ? (tid >> 2) + 64 : (tid >> 2) - 32;  vc2[1] = (tid >= 128);
  vd[2] = (tid >> 2) + 32;               vc2[2] = 1;
#pragma unroll
  for (int j = 0; j < 3; ++j) vgq[j] = qs ^ swz(vd[j]);

  uint4 kreg[3], vreg[3];
#pragma unroll
  for (int j = 0; j < 3; ++j) {          // prefetch tile 0
    kreg[j] = *(const uint4*)(kk + ((size_t)bh * 1024 + key_s) * 96 + (j * 4 + kgq) * 8);
    vreg[j] = *(const uint4*)(vT + ((size_t)bh * 96 + vd[j]) * 1024 + vc2[j] * 32 + vgq[j] * 8);
  }

  for (int t = 0; t < 16; ++t) {
    __syncthreads();                     // all waves done reading prev tile
#pragma unroll
    for (int j = 0; j < 3; ++j) {
      *(uint4*)(KVs + (size_t)(j * 256 + tid) * 8) = kreg[j];
      *(uint4*)(KVs + (size_t)(768 + j * 256 + tid) * 8) = vreg[j];
    }
    __syncthreads();
    if (t < 15) {                        // prefetch next tile during compute
      const int kt0 = (t + 1) * 64;
#pragma unroll
      for (int j = 0; j < 3; ++j) {
        kreg[j] = *(const uint4*)(kk + ((size_t)bh * 1024 + kt0 + key_s) * 96 + (j * 4 + kgq) * 8);
        vreg[j] = *(const uint4*)(vT + ((size_t)bh * 96 + vd[j]) * 1024 + kt0 + vc2[j] * 32 + vgq[j] * 8);
      }
    }
    // ---- S^T phase: S^T = K*Q^T; C-regs = 4 consecutive keys ----
#pragma unroll
    for (int kt = 0; kt < 4; ++kt) {
      bf16x8 af[3];                      // A=K: m=i15 -> key, k=quad*8+j -> d
#pragma unroll
      for (int c = 0; c < 3; ++c)
        af[c] = *(const bf16x8*)(KVs + ((size_t)((c * 64 + kt * 16 + i15) * 4) + (quad ^ xs)) * 8);
      f32x4 s = (f32x4){0.f, 0.f, 0.f, 0.f};
#pragma unroll
      for (int c = 0; c < 3; ++c)
        s = __builtin_amdgcn_mfma_f32_16x16x32_bf16(af[c], qf[c], s, 0, 0, 0);
      // C-layout: row=key=kt*16+quad*4+r, col=qrow=i15
      const float e0 = __expf(s[0]), e1 = __expf(s[1]);
      const float e2 = __expf(s[2]), e3 = __expf(s[3]);
      l += (e0 + e1) + (e2 + e3);
      uint2 pk;
      pk.x = (u32)f2b(e0) | ((u32)f2b(e1) << 16);
      pk.y = (u32)f2b(e2) | ((u32)f2b(e3) << 16);
      const int pg = (kt & 1) * 2 + (quad >> 1);           // granule within 32-key chunk
      *(uint2*)(Pw + (size_t)(((kt >> 1) * 16 + i15) * 4 + (pg ^ xs)) * 8
                    + (quad & 1) * 4) = pk;
    }
    // ---- PV phase: O[qrow][d] += P*V ----
#pragma unroll
    for (int c2 = 0; c2 < 2; ++c2) {
      const bf16x8 pa = *(const bf16x8*)(Pw + (size_t)((c2 * 16 + i15) * 4 + (quad ^ xs)) * 8);
#pragma unroll
      for (int dt = 0; dt < 6; ++dt) {
        const bf16x8 vb = *(const bf16x8*)(KVs +
            ((size_t)(768 + (c2 * 96 + dt * 16 + i15) * 4) + (quad ^ xs)) * 8);
        o[dt] = __builtin_amdgcn_mfma_f32_16x16x32_bf16(pa, vb, o[dt], 0, 0, 0);
      }
    }
  }

  // ---- epilogue: reduce l across key-lanes, divide, coalesced stores ------
  l += __shfl_xor(l, 16); l += __shfl_xor(l, 32);
  __syncthreads();                       // everyone past last PV; smem reusable
  u16* scr = smem + w * 1664;            // 16 rows x stride 104 (16B-aligned)
#pragma unroll
  for (int r = 0; r < 4; ++r) {
    const float linv = 1.f / __shfl(l, quad * 4 + r);
    const int row16 = quad * 4 + r;      // o C-layout: row=qrow16, col=d(i15)
#pragma unroll
    for (int dt = 0; dt < 6; ++dt)
      scr[row16 * 104 + dt * 16 + i15] = f2b(o[dt][r] * linv);
  }
#pragma unroll
  for (int jj = 0; jj < 3; ++jj) {       // 192 uint4 per wave, 192B/row coalesced
    const int id = jj * 64 + lane;
    const int row16 = id / 12, g = id - row16 * 12;
    const int grow = b * 1024 + qbase + w * 16 + row16;
    *(uint4*)(ctx + (size_t)grow * 768 + h * 96 + g * 8) =
        *(const uint4*)(scr + row16 * 104 + g * 8);
  }
}

// ---------------- proj GEMM: 128x64 tiles, ctx @ wT + bias -> out fp32 ------
__global__ __launch_bounds__(256, 4) void proj_gemm_kernel(
    const u16* __restrict__ ctx, const u16* __restrict__ wT,
    const float* __restrict__ bias, float* __restrict__ out) {
  f32x4 acc[4][2];
  const int bid = blockIdx.x;                 // 768 blocks = 3/CU exact
  const int xcd = bid & 7, slot = bid >> 3;   // 96 slots per XCD
  const int mb = xcd * 8 + slot / 12, nb = slot % 12;
  const int m0 = mb * 128, n0 = nb * 64;
  gemm_core<64>(ctx, wT, m0, n0, acc);

  const int tid = threadIdx.x, w = tid >> 6, lane = tid & 63;
  const int i15 = lane & 15, quad = lane >> 4;
  const int wm = (w >> 1) * 64, wn = (w & 1) * 32;
#pragma unroll
  for (int jt = 0; jt < 2; ++jt) {
    const int c = n0 + wn + jt * 16 + i15;
    const float bb = bias[c];
#pragma unroll
    for (int it = 0; it < 4; ++it) {
#pragma unroll
      for (int r = 0; r < 4; ++r) {
        const int m = m0 + wm + it * 16 + quad * 4 + r;
        out[(size_t)m * 768 + c] = acc[it][jt][r] + bb;
      }
    }
  }
}

// ---------------- host launcher --------------------------------------------
extern "C" void kernel_launch(void* const* d_in, const int* in_sizes, int n_in,
                              void* d_out, int out_size, void* d_ws, size_t ws_size,
                              hipStream_t stream) {
  const float* x      = (const float*)d_in[0];   // [8,1024,768]
  const float* w_qkv  = (const float*)d_in[1];   // [768,2304]
  const float* temp   = (const float*)d_in[2];   // [8]
  const float* w_proj = (const float*)d_in[3];   // [768,768]
  const float* b_proj = (const float*)d_in[4];   // [768]

  u16* ws      = (u16*)d_ws;
  u16* xb      = ws;                     // 8192*768
  u16* wqkvT   = xb + 6291456;           // 2304*768
  u16* qb      = wqkvT + 1769472;        // 64*1024*96
  u16* kb      = qb + 6291456;
  u16* vTb     = kb + 6291456;           // 64*96*1024 (transposed)
  u16* ctxb    = vTb + 6291456;          // 8192*768
  u16* wprojT  = ctxb + 6291456;         // 768*768

  prep_kernel<<<8448, 256, 0, stream>>>(x, w_qkv, w_proj, xb, wqkvT, wprojT);
  qkv_gemm_kernel<<<768, 256, 0, stream>>>(xb, wqkvT, temp, qb, kb, vTb);
  attn_kernel<<<1024, 256, 0, stream>>>(qb, kb, vTb, ctxb);
  proj_gemm_kernel<<<768, 256, 0, stream>>>(ctxb, wprojT, b_proj, (float*)d_out);
}

// Round 7
// 208.810 us; speedup vs baseline: 1.2848x; 1.2848x over previous
//
#include <hip/hip_runtime.h>
#include <math.h>

typedef __attribute__((ext_vector_type(8))) short bf16x8;   // 8 bf16 = 4 VGPRs (MFMA A/B frag)
typedef __attribute__((ext_vector_type(4))) float f32x4;    // MFMA C/D frag
typedef unsigned short u16;
typedef unsigned int u32;

// Problem: B=8, N=1024, C=768, H=8, hd=96.  BH=64 combined batch-heads.

__device__ __forceinline__ u16 f2b(float f) {               // fp32 -> bf16 RNE
  u32 u = __float_as_uint(f);
  return (u16)((u + 0x7fffu + ((u >> 16) & 1u)) >> 16);
}
__device__ __forceinline__ float b2f(u16 h) {
  return __uint_as_float(((u32)h) << 16);
}
__device__ __forceinline__ int swz(int m) { return (m ^ (m >> 2)) & 3; }

__device__ __forceinline__ void async16(const void* g, void* l) {
  __builtin_amdgcn_global_load_lds((const __attribute__((address_space(1))) u32*)g,
                                   (__attribute__((address_space(3))) u32*)l, 16, 0, 0);
}

// ---------------- prep: cast x, transpose+cast w_qkv and w_proj -------------
__global__ __launch_bounds__(256) void prep_kernel(const float* __restrict__ x,
                                                   const float* __restrict__ w_qkv,
                                                   const float* __restrict__ w_proj,
                                                   u16* __restrict__ xb,
                                                   u16* __restrict__ wqkvT,
                                                   u16* __restrict__ wprojT) {
  __shared__ float t[32][33];
  const int blk = blockIdx.x;
  if (blk < 6144) {                       // cast x -> bf16
    const int idx = blk * 256 + threadIdx.x;
    const float4 v = ((const float4*)x)[idx];
    uint2 o;
    o.x = (u32)f2b(v.x) | ((u32)f2b(v.y) << 16);
    o.y = (u32)f2b(v.z) | ((u32)f2b(v.w) << 16);
    ((uint2*)xb)[idx] = o;
    return;
  }
  const float* in; u16* out; int R, C, bx, by;
  if (blk < 6144 + 1728) {                // w_qkv [768,2304] -> [2304,768]
    const int rem = blk - 6144;
    in = w_qkv; out = wqkvT; R = 768; C = 2304; bx = rem % 72; by = rem / 72;
  } else {                                // w_proj [768,768] -> [768,768]
    const int rem = blk - 6144 - 1728;
    in = w_proj; out = wprojT; R = 768; C = 768; bx = rem % 24; by = rem / 24;
  }
  const int c0 = bx * 32, r0 = by * 32;
  const int tc = threadIdx.x & 31, tr = threadIdx.x >> 5;
#pragma unroll
  for (int j = 0; j < 4; ++j)
    t[tr + j * 8][tc] = in[(size_t)(r0 + tr + j * 8) * C + c0 + tc];
  __syncthreads();
#pragma unroll
  for (int j = 0; j < 4; ++j)
    out[(size_t)(c0 + tr + j * 8) * R + r0 + tc] = f2b(t[tc][tr + j * 8]);
}

// ---------------- 128xNT bf16 MFMA GEMM core (K=768), NT in {64,192} --------
// GATHER_A: A is logically [8192][768] but stored head-blocked as
// ctx[bh][n][96] — staging computes the gathered address (granules never
// cross heads, so coalescing/alignment is preserved).
template<int NT, bool GATHER_A>
__device__ __forceinline__ void gemm_core(const u16* __restrict__ A,
                                          const u16* __restrict__ Bt,
                                          int m0, int n0, f32x4 acc[4][NT / 32]) {
  constexpr int JT = NT / 32;
  constexpr int NINST = (512 + NT * 4) / 256;
  __shared__ u16 Sm[(512 + NT * 4) * 8];
  const int tid = threadIdx.x;
  const int w = tid >> 6, lane = tid & 63;
  const int i15 = lane & 15, quad = lane >> 4;
  const int wm = (w >> 1) * 64, wn = (w & 1) * (NT / 2);
  const int sw = quad ^ swz(i15);

#pragma unroll
  for (int i = 0; i < 4; ++i)
#pragma unroll
    for (int j = 0; j < JT; ++j) acc[i][j] = (f32x4){0.f, 0.f, 0.f, 0.f};

  for (int k0 = 0; k0 < 768; k0 += 32) {
    __syncthreads();
#pragma unroll
    for (int inst = 0; inst < NINST; ++inst) {
      const int s = inst * 256 + tid;          // granule slot (per lane)
      const u16* src;
      if (inst < 2) {                          // A region (slots < 512)
        const int m = s >> 2, e = s & 3;
        const int kg = e ^ swz(m);
        if (GATHER_A) {
          const int gm = m0 + m;
          const int bb = gm >> 10, nn = gm & 1023;
          const int g = (k0 >> 3) + kg;        // granule 0..95 within the row
          const int hh = g / 12, dd = g - hh * 12;
          src = A + (((size_t)(bb * 8 + hh) * 1024 + nn) * 96 + dd * 8);
        } else {
          src = A + ((size_t)(m0 + m) * 768 + k0 + kg * 8);
        }
      } else {                                 // B region
        const int s2 = s - 512;
        const int n = s2 >> 2, e = s2 & 3;
        src = Bt + ((size_t)(n0 + n) * 768 + k0 + (e ^ swz(n)) * 8);
      }
      async16(src, (void*)(Sm + (size_t)(inst * 256 + w * 64) * 8));
    }
    __syncthreads();                           // drains vmcnt before reads
    bf16x8 af[4], bf[JT];
#pragma unroll
    for (int i = 0; i < 4; ++i)
      af[i] = *(const bf16x8*)(Sm + ((size_t)(wm + i * 16 + i15) * 4 + sw) * 8);
#pragma unroll
    for (int j = 0; j < JT; ++j)
      bf[j] = *(const bf16x8*)(Sm + ((size_t)512 + (wn + j * 16 + i15) * 4 + sw) * 8);
#pragma unroll
    for (int i = 0; i < 4; ++i)
#pragma unroll
      for (int j = 0; j < JT; ++j)
        acc[i][j] = __builtin_amdgcn_mfma_f32_16x16x32_bf16(af[i], bf[j], acc[i][j], 0, 0, 0);
  }
}

// ---------------- qkv GEMM + fused L2norm/temp epilogue ---------------------
__global__ __launch_bounds__(256, 3) void qkv_gemm_kernel(
    const u16* __restrict__ xb, const u16* __restrict__ wT,
    const float* __restrict__ temp,
    u16* __restrict__ q, u16* __restrict__ k, u16* __restrict__ vT) {
  f32x4 acc[4][6];
  const int bid = blockIdx.x;                 // 768 blocks = 3/CU exact
  const int xcd = bid & 7, slot = bid >> 3;   // 96 slots per XCD
  const int mb = xcd * 8 + slot / 12, nb = slot % 12;
  const int m0 = mb * 128, n0 = nb * 192;
  gemm_core<192, false>(xb, wT, m0, n0, acc);

  const int tid = threadIdx.x, w = tid >> 6, lane = tid & 63;
  const int i15 = lane & 15, quad = lane >> 4;
  const int wm = (w >> 1) * 64;
  const int three = nb >> 2;                  // 0=q, 1=k, 2=v
  const int h = ((nb & 3) << 1) + (w & 1);    // wave-uniform head

  if (three < 2) {
    u16* dst = three ? k : q;
    const float sc_extra = three ? 1.f : temp[h];
#pragma unroll
    for (int it = 0; it < 4; ++it) {
#pragma unroll
      for (int r = 0; r < 4; ++r) {
        float s = 0.f;
#pragma unroll
        for (int jt = 0; jt < 6; ++jt) s += acc[it][jt][r] * acc[it][jt][r];
        s += __shfl_xor(s, 1); s += __shfl_xor(s, 2);
        s += __shfl_xor(s, 4); s += __shfl_xor(s, 8);
        const float scale = sc_extra / fmaxf(sqrtf(s), 1e-12f);
        const int m = m0 + wm + it * 16 + quad * 4 + r;
        const int b = m >> 10, n = m & 1023;
        u16* rowp = dst + ((size_t)(b * 8 + h) * 1024 + n) * 96;
#pragma unroll
        for (int jt = 0; jt < 6; ++jt)
          rowp[jt * 16 + i15] = f2b(acc[it][jt][r] * scale);
      }
    }
  } else {
#pragma unroll
    for (int it = 0; it < 4; ++it) {
      const int mb4 = m0 + wm + it * 16 + quad * 4;
      const int b = mb4 >> 10, nbase = mb4 & 1023;
#pragma unroll
      for (int jt = 0; jt < 6; ++jt) {
        const int d = jt * 16 + i15;
        uint2 pk;
        pk.x = (u32)f2b(acc[it][jt][0]) | ((u32)f2b(acc[it][jt][1]) << 16);
        pk.y = (u32)f2b(acc[it][jt][2]) | ((u32)f2b(acc[it][jt][3]) << 16);
        *(uint2*)(vT + ((size_t)(b * 8 + h) * 96 + d) * 1024 + nbase) = pk;
      }
    }
  }
}

// ---------------- fused attention (R4 geometry) + per-bh ctx layout ---------
// Block = (bh, 128 q-rows); 512 blocks, 2/CU. ctx is [bh][n][96]: each block
// writes one private contiguous 24-KB span -> no cross-XCD line sharing (R4's
// 57 MB / R6's 327 MB write amplification came from head-interleaved ctx rows
// being split across non-coherent per-XCD L2s at 128B-line granularity).
__global__ __launch_bounds__(256, 2) void attn_kernel(
    const u16* __restrict__ q, const u16* __restrict__ kk,
    const u16* __restrict__ vT, u16* __restrict__ ctx) {
  __shared__ u16 smem[20480];         // [0,12288): K+V granules; [12288,20480): Ps
  u16* KVs = smem;
  const int tid = threadIdx.x, w = tid >> 6, lane = tid & 63;
  const int i15 = lane & 15, quad = lane >> 4;
  const int xs = swz(i15);
  const int bh = blockIdx.x & 63;     // same bh -> same XCD (L2-resident K/V)
  const int qbase = (blockIdx.x >> 6) * 128;
  u16* Pw = smem + 12288 + w * 2048;  // per-wave P: 256 granules

  bf16x8 qf[2][3];
#pragma unroll
  for (int rt = 0; rt < 2; ++rt) {
    const int qrow = qbase + w * 32 + rt * 16 + i15;
    const u16* qp = q + ((size_t)bh * 1024 + qrow) * 96 + quad * 8;
#pragma unroll
    for (int c = 0; c < 3; ++c) qf[rt][c] = *(const bf16x8*)(qp + c * 32);
  }

  f32x4 o[2][6];
#pragma unroll
  for (int rt = 0; rt < 2; ++rt)
#pragma unroll
    for (int dt = 0; dt < 6; ++dt) o[rt][dt] = (f32x4){0.f, 0.f, 0.f, 0.f};
  float l[2] = {0.f, 0.f};

  const int key_s = tid >> 2, qs = tid & 3;
  const int kgq = qs ^ swz(key_s);
  int vd[3], vc2[3], vgq[3];
  vd[0] = tid >> 2;                      vc2[0] = 0;
  vd[1] = (tid < 128) ? (tid >> 2) + 64 : (tid >> 2) - 32;  vc2[1] = (tid >= 128);
  vd[2] = (tid >> 2) + 32;               vc2[2] = 1;
#pragma unroll
  for (int j = 0; j < 3; ++j) vgq[j] = qs ^ swz(vd[j]);

  uint4 kreg[3], vreg[3];
#pragma unroll
  for (int j = 0; j < 3; ++j) {          // prefetch tile 0
    kreg[j] = *(const uint4*)(kk + ((size_t)bh * 1024 + key_s) * 96 + (j * 4 + kgq) * 8);
    vreg[j] = *(const uint4*)(vT + ((size_t)bh * 96 + vd[j]) * 1024 + vc2[j] * 32 + vgq[j] * 8);
  }

  for (int t = 0; t < 16; ++t) {
    __syncthreads();                     // all waves done reading prev tile
#pragma unroll
    for (int j = 0; j < 3; ++j) {
      *(uint4*)(KVs + (size_t)(j * 256 + tid) * 8) = kreg[j];
      *(uint4*)(KVs + (size_t)(768 + j * 256 + tid) * 8) = vreg[j];
    }
    __syncthreads();
    if (t < 15) {                        // prefetch next tile during compute
      const int kt0 = (t + 1) * 64;
#pragma unroll
      for (int j = 0; j < 3; ++j) {
        kreg[j] = *(const uint4*)(kk + ((size_t)bh * 1024 + kt0 + key_s) * 96 + (j * 4 + kgq) * 8);
        vreg[j] = *(const uint4*)(vT + ((size_t)bh * 96 + vd[j]) * 1024 + kt0 + vc2[j] * 32 + vgq[j] * 8);
      }
    }
    // ---- S^T phase: S^T = K*Q^T; C-regs = 4 consecutive keys ----
#pragma unroll
    for (int kt = 0; kt < 4; ++kt) {
      bf16x8 af[3];                      // A=K: m=i15 -> key, k=quad*8+j -> d
#pragma unroll
      for (int c = 0; c < 3; ++c)
        af[c] = *(const bf16x8*)(KVs + ((size_t)((c * 64 + kt * 16 + i15) * 4) + (quad ^ xs)) * 8);
#pragma unroll
      for (int rt = 0; rt < 2; ++rt) {
        f32x4 s = (f32x4){0.f, 0.f, 0.f, 0.f};
#pragma unroll
        for (int c = 0; c < 3; ++c)
          s = __builtin_amdgcn_mfma_f32_16x16x32_bf16(af[c], qf[rt][c], s, 0, 0, 0);
        // C-layout: row=key=kt*16+quad*4+r, col=qrow=rt*16+i15
        const float e0 = __expf(s[0]), e1 = __expf(s[1]);
        const float e2 = __expf(s[2]), e3 = __expf(s[3]);
        l[rt] += (e0 + e1) + (e2 + e3);
        uint2 pk;
        pk.x = (u32)f2b(e0) | ((u32)f2b(e1) << 16);
        pk.y = (u32)f2b(e2) | ((u32)f2b(e3) << 16);
        const int pg = (kt & 1) * 2 + (quad >> 1);
        *(uint2*)(Pw + (size_t)(((kt >> 1) * 32 + rt * 16 + i15) * 4 + (pg ^ xs)) * 8
                      + (quad & 1) * 4) = pk;
      }
    }
    // ---- PV phase ----
#pragma unroll
    for (int c2 = 0; c2 < 2; ++c2) {
      bf16x8 pa[2];
#pragma unroll
      for (int rt = 0; rt < 2; ++rt)
        pa[rt] = *(const bf16x8*)(Pw + (size_t)((c2 * 32 + rt * 16 + i15) * 4 + (quad ^ xs)) * 8);
#pragma unroll
      for (int dt = 0; dt < 6; ++dt) {
        const bf16x8 vb = *(const bf16x8*)(KVs +
            ((size_t)(768 + (c2 * 96 + dt * 16 + i15) * 4) + (quad ^ xs)) * 8);
#pragma unroll
        for (int rt = 0; rt < 2; ++rt)
          o[rt][dt] = __builtin_amdgcn_mfma_f32_16x16x32_bf16(pa[rt], vb, o[rt][dt], 0, 0, 0);
      }
    }
  }

  // ---- epilogue: reduce l, LDS round-trip, fully-linear uint4 stores ------
  l[0] += __shfl_xor(l[0], 16); l[0] += __shfl_xor(l[0], 32);
  l[1] += __shfl_xor(l[1], 16); l[1] += __shfl_xor(l[1], 32);
  __syncthreads();                       // everyone past last PV; smem reusable
  u16* scr = smem + w * 5120;            // 32 rows x stride 104 (16B-aligned)
#pragma unroll
  for (int rt = 0; rt < 2; ++rt) {
#pragma unroll
    for (int r = 0; r < 4; ++r) {
      const float linv = 1.f / __shfl(l[rt], quad * 4 + r);
      const int row32 = rt * 16 + quad * 4 + r;
#pragma unroll
      for (int dt = 0; dt < 6; ++dt)
        scr[row32 * 104 + dt * 16 + i15] = f2b(o[rt][dt][r] * linv);
    }
  }
  // ctx[bh][n][96]: wave's 32 rows = 6 KB contiguous; elem offset = id*8
  u16* gbase = ctx + ((size_t)bh * 1024 + qbase + w * 32) * 96;
#pragma unroll
  for (int jj = 0; jj < 6; ++jj) {
    const int id = jj * 64 + lane;
    const int row32 = id / 12, g = id - row32 * 12;
    *(uint4*)(gbase + (size_t)id * 8) = *(const uint4*)(scr + row32 * 104 + g * 8);
  }
}

// ---------------- proj GEMM: A gathered from ctx[bh][n][96] -----------------
__global__ __launch_bounds__(256, 4) void proj_gemm_kernel(
    const u16* __restrict__ ctx, const u16* __restrict__ wT,
    const float* __restrict__ bias, float* __restrict__ out) {
  f32x4 acc[4][2];
  const int bid = blockIdx.x;                 // 768 blocks = 3/CU exact
  const int xcd = bid & 7, slot = bid >> 3;   // 96 slots per XCD
  const int mb = xcd * 8 + slot / 12, nb = slot % 12;
  const int m0 = mb * 128, n0 = nb * 64;
  gemm_core<64, true>(ctx, wT, m0, n0, acc);

  const int tid = threadIdx.x, w = tid >> 6, lane = tid & 63;
  const int i15 = lane & 15, quad = lane >> 4;
  const int wm = (w >> 1) * 64, wn = (w & 1) * 32;
#pragma unroll
  for (int jt = 0; jt < 2; ++jt) {
    const int c = n0 + wn + jt * 16 + i15;
    const float bb = bias[c];
#pragma unroll
    for (int it = 0; it < 4; ++it) {
#pragma unroll
      for (int r = 0; r < 4; ++r) {
        const int m = m0 + wm + it * 16 + quad * 4 + r;
        out[(size_t)m * 768 + c] = acc[it][jt][r] + bb;
      }
    }
  }
}

// ---------------- host launcher --------------------------------------------
extern "C" void kernel_launch(void* const* d_in, const int* in_sizes, int n_in,
                              void* d_out, int out_size, void* d_ws, size_t ws_size,
                              hipStream_t stream) {
  const float* x      = (const float*)d_in[0];   // [8,1024,768]
  const float* w_qkv  = (const float*)d_in[1];   // [768,2304]
  const float* temp   = (const float*)d_in[2];   // [8]
  const float* w_proj = (const float*)d_in[3];   // [768,768]
  const float* b_proj = (const float*)d_in[4];   // [768]

  u16* ws      = (u16*)d_ws;
  u16* xb      = ws;                     // 8192*768
  u16* wqkvT   = xb + 6291456;           // 2304*768
  u16* qb      = wqkvT + 1769472;        // 64*1024*96
  u16* kb      = qb + 6291456;
  u16* vTb     = kb + 6291456;           // 64*96*1024 (transposed)
  u16* ctxb    = vTb + 6291456;          // [bh][n][96] head-blocked
  u16* wprojT  = ctxb + 6291456;         // 768*768

  prep_kernel<<<8448, 256, 0, stream>>>(x, w_qkv, w_proj, xb, wqkvT, wprojT);
  qkv_gemm_kernel<<<768, 256, 0, stream>>>(xb, wqkvT, temp, qb, kb, vTb);
  attn_kernel<<<512, 256, 0, stream>>>(qb, kb, vTb, ctxb);
  proj_gemm_kernel<<<768, 256, 0, stream>>>(ctxb, wprojT, b_proj, (float*)d_out);
}